// Round 1
// baseline (356.482 us; speedup 1.0000x reference)
//
#include <hip/hip_runtime.h>

#define B_ROWS 16384
#define FEAT   2048
#define MARGIN 1.0f

__global__ void tl_init_out(float* __restrict__ out) {
    out[0] = 0.0f;
}

__global__ __launch_bounds__(256) void TripletLoss_90091234001212_kernel(
    const float* __restrict__ anc,
    const float* __restrict__ pos,
    const float* __restrict__ neg,
    float* __restrict__ out)
{
    const int wave = threadIdx.x >> 6;      // 0..3
    const int lane = threadIdx.x & 63;
    const int row  = blockIdx.x * 4 + wave;

    const float4* a4 = (const float4*)(anc + (size_t)row * FEAT);
    const float4* p4 = (const float4*)(pos + (size_t)row * FEAT);
    const float4* n4 = (const float4*)(neg + (size_t)row * FEAT);

    float dp = 0.0f, dn = 0.0f;

    // FEAT/4 = 512 float4 per row; 64 lanes x 8 iters, stride 64 -> coalesced
    #pragma unroll
    for (int it = 0; it < 8; ++it) {
        const int idx = it * 64 + lane;
        const float4 av = a4[idx];
        const float4 pv = p4[idx];
        const float4 nv = n4[idx];
        float d;
        d = av.x - pv.x; dp += d * d;
        d = av.y - pv.y; dp += d * d;
        d = av.z - pv.z; dp += d * d;
        d = av.w - pv.w; dp += d * d;
        d = av.x - nv.x; dn += d * d;
        d = av.y - nv.y; dn += d * d;
        d = av.z - nv.z; dn += d * d;
        d = av.w - nv.w; dn += d * d;
    }

    // wave-64 butterfly reduce (two values)
    #pragma unroll
    for (int off = 32; off > 0; off >>= 1) {
        dp += __shfl_down(dp, off);
        dn += __shfl_down(dn, off);
    }

    __shared__ float partial[4];
    if (lane == 0) {
        const float loss = sqrtf(dp) - sqrtf(dn) + MARGIN;
        partial[wave] = fmaxf(loss, 0.0f) * (1.0f / (float)B_ROWS);
    }
    __syncthreads();

    if (threadIdx.x == 0) {
        atomicAdd(out, partial[0] + partial[1] + partial[2] + partial[3]);
    }
}

extern "C" void kernel_launch(void* const* d_in, const int* in_sizes, int n_in,
                              void* d_out, int out_size, void* d_ws, size_t ws_size,
                              hipStream_t stream) {
    const float* anc = (const float*)d_in[0];
    const float* pos = (const float*)d_in[1];
    const float* neg = (const float*)d_in[2];
    float* out = (float*)d_out;

    tl_init_out<<<1, 1, 0, stream>>>(out);

    const int rows_per_block = 4;
    const int grid = B_ROWS / rows_per_block;  // 4096
    TripletLoss_90091234001212_kernel<<<grid, 256, 0, stream>>>(anc, pos, neg, out);
}

// Round 2
// 348.976 us; speedup vs baseline: 1.0215x; 1.0215x over previous
//
#include <hip/hip_runtime.h>

#define B_ROWS 16384
#define FEAT   2048
#define MARGIN 1.0f
#define GRID1  4096   // 4 rows per block, one row per wave

// Stage 1: one wave per row, per-block partial sums -> ws (no atomics)
__global__ __launch_bounds__(256) void TripletLoss_90091234001212_kernel(
    const float* __restrict__ anc,
    const float* __restrict__ pos,
    const float* __restrict__ neg,
    float* __restrict__ ws)
{
    const int wave = threadIdx.x >> 6;      // 0..3
    const int lane = threadIdx.x & 63;
    const int row  = blockIdx.x * 4 + wave;

    const float4* a4 = (const float4*)(anc + (size_t)row * FEAT);
    const float4* p4 = (const float4*)(pos + (size_t)row * FEAT);
    const float4* n4 = (const float4*)(neg + (size_t)row * FEAT);

    float dp = 0.0f, dn = 0.0f;

    // FEAT/4 = 512 float4 per row; 64 lanes x 8 iters, stride 64 -> coalesced
    #pragma unroll
    for (int it = 0; it < 8; ++it) {
        const int idx = it * 64 + lane;
        const float4 av = a4[idx];
        const float4 pv = p4[idx];
        const float4 nv = n4[idx];
        float d;
        d = av.x - pv.x; dp += d * d;
        d = av.y - pv.y; dp += d * d;
        d = av.z - pv.z; dp += d * d;
        d = av.w - pv.w; dp += d * d;
        d = av.x - nv.x; dn += d * d;
        d = av.y - nv.y; dn += d * d;
        d = av.z - nv.z; dn += d * d;
        d = av.w - nv.w; dn += d * d;
    }

    // wave-64 butterfly reduce (two values)
    #pragma unroll
    for (int off = 32; off > 0; off >>= 1) {
        dp += __shfl_down(dp, off);
        dn += __shfl_down(dn, off);
    }

    __shared__ float partial[4];
    if (lane == 0) {
        const float loss = sqrtf(dp) - sqrtf(dn) + MARGIN;
        partial[wave] = fmaxf(loss, 0.0f);
    }
    __syncthreads();

    if (threadIdx.x == 0) {
        ws[blockIdx.x] = partial[0] + partial[1] + partial[2] + partial[3];
    }
}

// Stage 2: reduce GRID1 partials -> out[0]
__global__ __launch_bounds__(256) void tl_reduce(
    const float* __restrict__ ws, float* __restrict__ out)
{
    const int tid  = threadIdx.x;
    const int lane = tid & 63;
    const int wave = tid >> 6;

    // 4096 / 256 = 16 floats per thread, coalesced float4 loads
    const float4* w4 = (const float4*)ws;
    float s = 0.0f;
    #pragma unroll
    for (int it = 0; it < 4; ++it) {
        const float4 v = w4[it * 256 + tid];
        s += v.x + v.y + v.z + v.w;
    }

    #pragma unroll
    for (int off = 32; off > 0; off >>= 1) {
        s += __shfl_down(s, off);
    }

    __shared__ float partial[4];
    if (lane == 0) partial[wave] = s;
    __syncthreads();

    if (tid == 0) {
        out[0] = (partial[0] + partial[1] + partial[2] + partial[3])
                 * (1.0f / (float)B_ROWS);
    }
}

extern "C" void kernel_launch(void* const* d_in, const int* in_sizes, int n_in,
                              void* d_out, int out_size, void* d_ws, size_t ws_size,
                              hipStream_t stream) {
    const float* anc = (const float*)d_in[0];
    const float* pos = (const float*)d_in[1];
    const float* neg = (const float*)d_in[2];
    float* out = (float*)d_out;
    float* ws  = (float*)d_ws;

    TripletLoss_90091234001212_kernel<<<GRID1, 256, 0, stream>>>(anc, pos, neg, ws);
    tl_reduce<<<1, 256, 0, stream>>>(ws, out);
}

// Round 4
// 318.883 us; speedup vs baseline: 1.1179x; 1.0944x over previous
//
#include <hip/hip_runtime.h>

#define B_ROWS 16384
#define FEAT   2048
#define MARGIN 1.0f

typedef float vfloat4 __attribute__((ext_vector_type(4)));

// Stage 1: one block (256 thr) per row; 2 float4 per thread per stream.
__global__ __launch_bounds__(256) void TripletLoss_90091234001212_kernel(
    const float* __restrict__ anc,
    const float* __restrict__ pos,
    const float* __restrict__ neg,
    float* __restrict__ ws)
{
    const int tid  = threadIdx.x;
    const int lane = tid & 63;
    const int wave = tid >> 6;
    const int row  = blockIdx.x;

    const vfloat4* a4 = (const vfloat4*)(anc + (size_t)row * FEAT);
    const vfloat4* p4 = (const vfloat4*)(pos + (size_t)row * FEAT);
    const vfloat4* n4 = (const vfloat4*)(neg + (size_t)row * FEAT);

    // 512 float4 per row / 256 threads = 2 per thread; 6 independent loads.
    const int i0 = tid;
    const int i1 = tid + 256;
    const vfloat4 a0 = __builtin_nontemporal_load(&a4[i0]);
    const vfloat4 a1 = __builtin_nontemporal_load(&a4[i1]);
    const vfloat4 p0 = __builtin_nontemporal_load(&p4[i0]);
    const vfloat4 p1 = __builtin_nontemporal_load(&p4[i1]);
    const vfloat4 n0 = __builtin_nontemporal_load(&n4[i0]);
    const vfloat4 n1 = __builtin_nontemporal_load(&n4[i1]);

    float dp = 0.0f, dn = 0.0f, d;
    d = a0.x - p0.x; dp += d * d;
    d = a0.y - p0.y; dp += d * d;
    d = a0.z - p0.z; dp += d * d;
    d = a0.w - p0.w; dp += d * d;
    d = a1.x - p1.x; dp += d * d;
    d = a1.y - p1.y; dp += d * d;
    d = a1.z - p1.z; dp += d * d;
    d = a1.w - p1.w; dp += d * d;
    d = a0.x - n0.x; dn += d * d;
    d = a0.y - n0.y; dn += d * d;
    d = a0.z - n0.z; dn += d * d;
    d = a0.w - n0.w; dn += d * d;
    d = a1.x - n1.x; dn += d * d;
    d = a1.y - n1.y; dn += d * d;
    d = a1.z - n1.z; dn += d * d;
    d = a1.w - n1.w; dn += d * d;

    // wave-64 butterfly reduce (two values)
    #pragma unroll
    for (int off = 32; off > 0; off >>= 1) {
        dp += __shfl_down(dp, off);
        dn += __shfl_down(dn, off);
    }

    __shared__ float sdp[4], sdn[4];
    if (lane == 0) { sdp[wave] = dp; sdn[wave] = dn; }
    __syncthreads();

    if (tid == 0) {
        const float tdp = sdp[0] + sdp[1] + sdp[2] + sdp[3];
        const float tdn = sdn[0] + sdn[1] + sdn[2] + sdn[3];
        const float loss = sqrtf(tdp) - sqrtf(tdn) + MARGIN;
        ws[row] = fmaxf(loss, 0.0f);
    }
}

// Stage 2: reduce B_ROWS partials -> out[0]
__global__ __launch_bounds__(256) void tl_reduce(
    const float* __restrict__ ws, float* __restrict__ out)
{
    const int tid  = threadIdx.x;
    const int lane = tid & 63;
    const int wave = tid >> 6;

    // 16384 floats = 4096 float4; 256 threads x 16 float4
    const vfloat4* w4 = (const vfloat4*)ws;
    float s = 0.0f;
    #pragma unroll
    for (int it = 0; it < 16; ++it) {
        const vfloat4 v = w4[it * 256 + tid];
        s += v.x + v.y + v.z + v.w;
    }

    #pragma unroll
    for (int off = 32; off > 0; off >>= 1) {
        s += __shfl_down(s, off);
    }

    __shared__ float partial[4];
    if (lane == 0) partial[wave] = s;
    __syncthreads();

    if (tid == 0) {
        out[0] = (partial[0] + partial[1] + partial[2] + partial[3])
                 * (1.0f / (float)B_ROWS);
    }
}

extern "C" void kernel_launch(void* const* d_in, const int* in_sizes, int n_in,
                              void* d_out, int out_size, void* d_ws, size_t ws_size,
                              hipStream_t stream) {
    const float* anc = (const float*)d_in[0];
    const float* pos = (const float*)d_in[1];
    const float* neg = (const float*)d_in[2];
    float* out = (float*)d_out;
    float* ws  = (float*)d_ws;

    TripletLoss_90091234001212_kernel<<<B_ROWS, 256, 0, stream>>>(anc, pos, neg, ws);
    tl_reduce<<<1, 256, 0, stream>>>(ws, out);
}